// Round 10
// baseline (502.141 us; speedup 1.0000x reference)
//
#include <hip/hip_runtime.h>

#define NC 32
#define NB 10
#define NH 64
#define REC 128  // ushorts per edge record (256B)

typedef __attribute__((ext_vector_type(8))) short bf16x8;
typedef __attribute__((ext_vector_type(4))) float f32x4;

static __device__ __forceinline__ unsigned short f2bf(float f) {
  union { float f; unsigned u; } v; v.f = f;
  unsigned r = v.u + 0x7fffu + ((v.u >> 16) & 1u);
  return (unsigned short)(r >> 16);
}
static __device__ __forceinline__ float bf2f(unsigned short b) {
  union { unsigned u; float f; } v; v.u = ((unsigned)b) << 16;
  return v.f;
}

// ---------------- prep (+ degree count fused) ----------------
__global__ void k_prep(const float* __restrict__ nattr, const float* __restrict__ ndeg,
                       const float* __restrict__ w0, const float* __restrict__ w1,
                       const float* __restrict__ w2, const float* __restrict__ w3,
                       const float* __restrict__ w4, const float* __restrict__ W1g,
                       const int* __restrict__ edst, int* __restrict__ cnt,
                       unsigned short* __restrict__ zb, float* __restrict__ dis,
                       unsigned short* __restrict__ wrp, unsigned short* __restrict__ w1p,
                       int N, int E) {
  int i = blockIdx.x * 256 + threadIdx.x;
  int nz = N * NC;
  if (i < nz) { zb[i] = f2bf(nattr[i]); return; }
  i -= nz;
  if (i < N) { dis[i] = rsqrtf(ndeg[i]); return; }
  i -= N;
  if (i < 5 * 32768) {
    int T = i >> 15, r = i & 32767;
    int t = r >> 9, l = (r >> 3) & 63, b = r & 7;
    int j = t * 16 + (l & 15);
    int u = j >> 5, k = j & 31, v = 8 * (l >> 4) + b;
    const float* w = (T == 0) ? w0 : (T == 1) ? w1 : (T == 2) ? w2 : (T == 3) ? w3 : w4;
    wrp[T * 32768 + (t * 64 + l) * 8 + b] = f2bf(w[u * 1024 + v * 32 + k] * (1.0f / 32.0f));
    return;
  }
  i -= 5 * 32768;
  if (i < 6144) {
    int c = i / 3072, r2 = i % 3072;
    int t = r2 >> 9, l = (r2 >> 3) & 63, b = r2 & 7;
    int k = 32 * c + 8 * (l >> 4) + b, col = 16 * t + (l & 15);
    w1p[i] = f2bf(W1g[k * 96 + col] * 0.125f);
    return;
  }
  i -= 6144;
  if (i < E) atomicAdd(&cnt[edst[i]], 1);
}

// ---------------- fused nf+mask fctp: 8 nodes/block, 2 tensor phases ----------------
__global__ __launch_bounds__(256) void k_nfmask(
    const unsigned short* __restrict__ wrp, const unsigned short* __restrict__ zb,
    const float* __restrict__ x_in, const float* __restrict__ dis,
    float* __restrict__ nf, float* __restrict__ maskb, int N) {
  __shared__ float zw[8 * 1024];
  __shared__ float xl[8][32];
  int tid = threadIdx.x;
  int lane = tid & 63, wv = tid >> 6;
  int nbase = blockIdx.x << 3;

  for (int i = tid; i < 8 * 32; i += 256) xl[i >> 5][i & 31] = x_in[nbase * 32 + i];

  int arow = lane & 15;
  bf16x8 af = {0,0,0,0,0,0,0,0};
  if (arow < 8) af = *(const bf16x8*)(zb + (nbase + arow) * 32 + 8 * (lane >> 4));

  int rb = 4 * (lane >> 4);
  int n = tid >> 5, k = tid & 31;
  for (int T = 0; T < 2; ++T) {
    f32x4 acc[16];
#pragma unroll
    for (int i2 = 0; i2 < 16; ++i2) {
      int t = wv * 16 + i2;
      bf16x8 bfr = *(const bf16x8*)(wrp + ((size_t)T * 32768) + ((size_t)t * 64 + lane) * 8);
      f32x4 z4 = {0.f, 0.f, 0.f, 0.f};
      acc[i2] = __builtin_amdgcn_mfma_f32_16x16x32_bf16(af, bfr, z4, 0, 0, 0);
    }
    __syncthreads();  // previous phase's step-2 done before overwrite
    if (rb < 8) {
#pragma unroll
      for (int i2 = 0; i2 < 16; ++i2) {
        int col = (wv * 16 + i2) * 16 + (lane & 15);
#pragma unroll
        for (int r = 0; r < 4; ++r) zw[(rb + r) * 1024 + col] = acc[i2][r];
      }
    }
    __syncthreads();
    float s = 0.f;
    const float* zr = &zw[n * 1024];
#pragma unroll
    for (int u = 0; u < 32; ++u) s = fmaf(xl[n][u], zr[u * 32 + k], s);
    int gn = nbase + n;
    if (T == 0) nf[gn * 32 + k] = s * dis[gn];
    else        maskb[gn * 32 + k] = s;
  }
}

// ---------------- CSR scans ----------------
__global__ __launch_bounds__(512) void k_scan1(const int* __restrict__ cnt, int* __restrict__ exl,
                                               int* __restrict__ bsum, int n) {
  __shared__ int s[512];
  int t = threadIdx.x;
  int i = blockIdx.x * 512 + t;
  int v = (i < n) ? cnt[i] : 0;
  s[t] = v;
  __syncthreads();
  for (int off = 1; off < 512; off <<= 1) {
    int add = (t >= off) ? s[t - off] : 0;
    __syncthreads();
    s[t] += add;
    __syncthreads();
  }
  if (i < n) exl[i] = s[t] - v;
  if (t == 511) bsum[blockIdx.x] = s[511];
}
__global__ void k_scan2(int* __restrict__ bsum, int nb) {
  __shared__ int s[128];
  int t = threadIdx.x;
  int v = (t < nb) ? bsum[t] : 0;
  s[t] = v;
  __syncthreads();
  for (int off = 1; off < 128; off <<= 1) {
    int add = (t >= off) ? s[t - off] : 0;
    __syncthreads();
    s[t] += add;
    __syncthreads();
  }
  if (t < nb) bsum[t] = s[t] - v;
}
__global__ void k_scan3(int* __restrict__ off, const int* __restrict__ bbase,
                        int* __restrict__ cur, int N, int E) {
  int i = blockIdx.x * 256 + threadIdx.x;
  if (i < N) {
    int o = off[i] + bbase[i >> 9];
    off[i] = o;
    cur[i] = o;
  } else if (i == N) {
    off[N] = E;
  }
}
__global__ void k_fill(const int* __restrict__ dst, int* __restrict__ cur,
                       int* __restrict__ pos, int E) {
  int i = blockIdx.x * 256 + threadIdx.x;
  if (i < E) pos[i] = atomicAdd(&cur[dst[i]], 1);
}

// ---------------- edge MLP -> unified 256B record scattered to CSR slot ----------------
#define TS 136  // LDS tile row stride in ushorts (272B, 16B-aligned, bank-staggered)
__global__ __launch_bounds__(256) void k_mlp(const float* __restrict__ el,
                                             const float* __restrict__ W0g,
                                             const unsigned short* __restrict__ w1p,
                                             const int* __restrict__ pos,
                                             const int* __restrict__ esrc,
                                             const float* __restrict__ eattr,
                                             unsigned short* __restrict__ recs, int E) {
  __shared__ float w0s[NB * NH];
  __shared__ __align__(16) unsigned short tile[64 * TS];
  __shared__ int posl[64];
  int tid = threadIdx.x;
  int ebase = blockIdx.x * 64;
  for (int i = tid; i < NB * NH; i += 256) w0s[i] = W0g[i] * 0.31622776601683794f;
  if (tid < 64) posl[tid] = pos[ebase + tid];

  // stage eattr (bf16) + src into record tail
  for (int i = tid; i < 64 * 10; i += 256) {
    int le = i / 10, c = i - le * 10;
    int e = ebase + le;
    if (c < 9) tile[le * TS + 96 + c] = f2bf(eattr[(size_t)e * 9 + c]);
    else       tile[le * TS + 105] = (unsigned short)esrc[e];
  }
  __syncthreads();

  int lane = tid & 63, wv = tid >> 6;
  int eloc0 = wv * 16;
  int erow = ebase + eloc0 + (lane & 15);
  float elr[NB];
#pragma unroll
  for (int b = 0; b < NB; ++b) elr[b] = el[erow * NB + b];
  int g8 = 8 * (lane >> 4);
  bf16x8 afr[2];
#pragma unroll
  for (int c = 0; c < 2; ++c) {
#pragma unroll
    for (int b = 0; b < 8; ++b) {
      int j = 32 * c + g8 + b;
      float p = 0.f;
#pragma unroll
      for (int q = 0; q < NB; ++q) p = fmaf(elr[q], w0s[q * NH + j], p);
      float h = p / (1.f + __expf(-p));
      afr[c][b] = (short)f2bf(h);
    }
  }
  f32x4 acc[6];
#pragma unroll
  for (int t = 0; t < 6; ++t) { f32x4 z4 = {0.f, 0.f, 0.f, 0.f}; acc[t] = z4; }
#pragma unroll
  for (int c = 0; c < 2; ++c) {
#pragma unroll
    for (int t = 0; t < 6; ++t) {
      bf16x8 bfr = *(const bf16x8*)(w1p + ((c * 6 + t) * 64 + lane) * 8);
      acc[t] = __builtin_amdgcn_mfma_f32_16x16x32_bf16(afr[c], bfr, acc[t], 0, 0, 0);
    }
  }
  int rb = 4 * (lane >> 4);
#pragma unroll
  for (int t = 0; t < 6; ++t) {
    int col = 16 * t + (lane & 15);
#pragma unroll
    for (int r = 0; r < 4; ++r) tile[(eloc0 + rb + r) * TS + col] = f2bf(acc[t][r]);
  }
  __syncthreads();
  // 16 x uint4 per row -> full 4-sector 256B scatter write
  for (int ch = tid; ch < 64 * 16; ch += 256) {
    int le = ch >> 4, seg = ch & 15;
    size_t p = (size_t)posl[le];
    *(uint4*)(recs + p * REC + seg * 8) = *(const uint4*)(&tile[le * TS + seg * 8]);
  }
}

// ---------------- gather: one wave per node, lane-halves alternate edges ----------------
__global__ __launch_bounds__(256) void k_gather(
    const int* __restrict__ off, const unsigned short* __restrict__ recs,
    const float* __restrict__ nf, const float* __restrict__ dis,
    float* __restrict__ a_all, int N) {
  int hw = blockIdx.x * 4 + (threadIdx.x >> 6);
  int lane = threadIdx.x & 63;
  int u = lane & 31, half = lane >> 5;
  if (hw >= N) return;
  int beg = off[hw], end = off[hw + 1];
  float a0 = 0, a1x = 0, a1y = 0, a1z = 0, b0 = 0, b1 = 0, b2 = 0, b3 = 0, b4 = 0;
  float xs_next = 0.f;
  int p0 = beg + half;
  if (p0 < end) {
    int s0 = recs[(size_t)p0 * REC + 105];
    xs_next = nf[(size_t)s0 * 32 + u];
  }
  for (int p = p0; p < end; p += 2) {
    float xs = xs_next;
    int p2 = p + 2;
    if (p2 < end) {
      int s2 = recs[(size_t)p2 * REC + 105];
      xs_next = nf[(size_t)s2 * 32 + u];
    }
    const unsigned short* r = recs + (size_t)p * REC;
    float w0 = bf2f(r[u]), w1 = bf2f(r[32 + u]), w2 = bf2f(r[64 + u]);
    float t0 = w0 * xs, t1 = w1 * xs, t2 = w2 * xs;
    a0  = fmaf(t0, bf2f(r[96]), a0);
    a1x = fmaf(t1, bf2f(r[97]), a1x);
    a1y = fmaf(t1, bf2f(r[98]), a1y);
    a1z = fmaf(t1, bf2f(r[99]), a1z);
    b0  = fmaf(t2, bf2f(r[100]), b0);
    b1  = fmaf(t2, bf2f(r[101]), b1);
    b2  = fmaf(t2, bf2f(r[102]), b2);
    b3  = fmaf(t2, bf2f(r[103]), b3);
    b4  = fmaf(t2, bf2f(r[104]), b4);
  }
  // cross-half reduce
  a0 += __shfl_xor(a0, 32, 64);  a1x += __shfl_xor(a1x, 32, 64);
  a1y += __shfl_xor(a1y, 32, 64); a1z += __shfl_xor(a1z, 32, 64);
  b0 += __shfl_xor(b0, 32, 64);  b1 += __shfl_xor(b1, 32, 64);
  b2 += __shfl_xor(b2, 32, 64);  b3 += __shfl_xor(b3, 32, 64);
  b4 += __shfl_xor(b4, 32, 64);
  if (half == 0) {
    float d = dis[hw];
    float* ar = a_all + (size_t)hw * 288;
    ar[0 * 32 + u] = a0 * d;
    ar[1 * 32 + u] = a1x * d;
    ar[2 * 32 + u] = a1y * d;
    ar[3 * 32 + u] = a1z * d;
    ar[4 * 32 + u] = b0 * d;
    ar[5 * 32 + u] = b1 * d;
    ar[6 * 32 + u] = b2 * d;
    ar[7 * 32 + u] = b3 * d;
    ar[8 * 32 + u] = b4 * d;
  }
}

// ---------------- fused output fctp: 8 nodes/block, 3 tensor phases ----------------
__global__ __launch_bounds__(256) void k_out(
    const unsigned short* __restrict__ wrp, const unsigned short* __restrict__ zb,
    const float* __restrict__ a_all, const float* __restrict__ maskb,
    float* __restrict__ out, int N) {
  __shared__ float zw[8 * 1024];
  __shared__ float xl[8][9][32];
  int tid = threadIdx.x;
  int lane = tid & 63, wv = tid >> 6;
  int nbase = blockIdx.x << 3;

  for (int i = tid; i < 8 * 288; i += 256) {
    int n2 = i / 288, rem = i - n2 * 288;
    xl[n2][rem >> 5][rem & 31] = a_all[(size_t)(nbase + n2) * 288 + rem];
  }

  int arow = lane & 15;
  bf16x8 af = {0,0,0,0,0,0,0,0};
  if (arow < 8) af = *(const bf16x8*)(zb + (nbase + arow) * 32 + 8 * (lane >> 4));

  const float c_s = 0.3826834323650898f;
  const float c_x = 0.9238795325112867f;
  int rb = 4 * (lane >> 4);
  int n = tid >> 5, k = tid & 31;
  const int nmT[3] = {1, 3, 5};
  const int moff[3] = {0, 1, 4};
  const int ooff[3] = {0, 32, 128};

  for (int T = 0; T < 3; ++T) {
    f32x4 acc[16];
#pragma unroll
    for (int i2 = 0; i2 < 16; ++i2) {
      int t = wv * 16 + i2;
      bf16x8 bfr = *(const bf16x8*)(wrp + ((size_t)(2 + T) * 32768) + ((size_t)t * 64 + lane) * 8);
      f32x4 z4 = {0.f, 0.f, 0.f, 0.f};
      acc[i2] = __builtin_amdgcn_mfma_f32_16x16x32_bf16(af, bfr, z4, 0, 0, 0);
    }
    __syncthreads();
    if (rb < 8) {
#pragma unroll
      for (int i2 = 0; i2 < 16; ++i2) {
        int col = (wv * 16 + i2) * 16 + (lane & 15);
#pragma unroll
        for (int r = 0; r < 4; ++r) zw[(rb + r) * 1024 + col] = acc[i2][r];
      }
    }
    __syncthreads();
    const float* zr = &zw[n * 1024];
    int gn = nbase + n;
    int nm = nmT[T];
    for (int m = 0; m < nm; ++m) {
      float s = 0.f;
      const float* xr = xl[n][moff[T] + m];
#pragma unroll
      for (int u = 0; u < 32; ++u) s = fmaf(xr[u], zr[u * 32 + k], s);
      if (T == 0) s = c_x * s + c_s * maskb[(size_t)gn * 32 + k];
      out[(size_t)gn * 288 + ooff[T] + k * nm + m] = s;
    }
  }
}

extern "C" void kernel_launch(void* const* d_in, const int* in_sizes, int n_in,
                              void* d_out, int out_size, void* d_ws, size_t ws_size,
                              hipStream_t stream) {
  const float* node_input = (const float*)d_in[0];
  const float* node_attr  = (const float*)d_in[1];
  const float* node_deg   = (const float*)d_in[2];
  const int*   edge_src   = (const int*)d_in[3];
  const int*   edge_dst   = (const int*)d_in[4];
  const float* edge_attr  = (const float*)d_in[5];
  const float* el_emb     = (const float*)d_in[6];
  const float* w_lin_in   = (const float*)d_in[7];
  const float* w_lin_mask = (const float*)d_in[8];
  const float* w_out0     = (const float*)d_in[9];
  const float* w_out1     = (const float*)d_in[10];
  const float* w_out2     = (const float*)d_in[11];
  const float* W0         = (const float*)d_in[12];
  const float* W1         = (const float*)d_in[13];
  int N = in_sizes[0] / 32;
  int E = in_sizes[3];
  float* out = (float*)d_out;

  char* p = (char*)d_ws;
  auto carve = [&](size_t bytes) { char* r = p; p += (bytes + 255) & ~(size_t)255; return r; };
  unsigned short* recs = (unsigned short*)carve((size_t)E * REC * 2);  // 153.6MB
  float* a_all        = (float*)carve((size_t)N * 288 * 4);
  float* nf           = (float*)carve((size_t)N * 32 * 4);
  float* maskb        = (float*)carve((size_t)N * 32 * 4);
  unsigned short* zb  = (unsigned short*)carve((size_t)N * 32 * 2);
  float* dis          = (float*)carve((size_t)N * 4);
  unsigned short* wrp = (unsigned short*)carve(5 * 32768 * 2);
  unsigned short* w1p = (unsigned short*)carve(6144 * 2);
  int* cnt            = (int*)carve((size_t)N * 4);
  int* off            = (int*)carve((size_t)(N + 1) * 4);
  int* cur            = (int*)carve((size_t)N * 4);
  int* pos            = (int*)carve((size_t)E * 4);
  int* bsum           = (int*)carve(1024);

  hipMemsetAsync(cnt, 0, (size_t)N * 4, stream);

  int tot = N * 32 + N + 5 * 32768 + 6144 + E;
  k_prep<<<(tot + 255) / 256, 256, 0, stream>>>(node_attr, node_deg, w_lin_in, w_lin_mask,
                                                w_out0, w_out1, w_out2, W1, edge_dst, cnt,
                                                zb, dis, wrp, w1p, N, E);

  k_nfmask<<<N / 8, 256, 0, stream>>>(wrp, zb, node_input, dis, nf, maskb, N);

  int nb1 = (N + 511) / 512;
  k_scan1<<<nb1, 512, 0, stream>>>(cnt, off, bsum, N);
  k_scan2<<<1, 128, 0, stream>>>(bsum, nb1);
  k_scan3<<<(N + 1 + 255) / 256, 256, 0, stream>>>(off, bsum, cur, N, E);
  k_fill<<<(E + 255) / 256, 256, 0, stream>>>(edge_dst, cur, pos, E);

  k_mlp<<<E / 64, 256, 0, stream>>>(el_emb, W0, w1p, pos, edge_src, edge_attr, recs, E);
  k_gather<<<(N + 3) / 4, 256, 0, stream>>>(off, recs, nf, dis, a_all, N);

  k_out<<<N / 8, 256, 0, stream>>>(wrp, zb, a_all, maskb, out, N);
}

// Round 14
// 428.306 us; speedup vs baseline: 1.1724x; 1.1724x over previous
//
#include <hip/hip_runtime.h>

#define NC 32
#define NB 10
#define NH 64
#define REC 128  // ushorts per edge record (256B)

typedef __attribute__((ext_vector_type(8))) short bf16x8;
typedef __attribute__((ext_vector_type(4))) float f32x4;
typedef _Float16 f16x8 __attribute__((ext_vector_type(8)));

static __device__ __forceinline__ unsigned short f2bf(float f) {
  union { float f; unsigned u; } v; v.f = f;
  unsigned r = v.u + 0x7fffu + ((v.u >> 16) & 1u);
  return (unsigned short)(r >> 16);
}
static __device__ __forceinline__ float bf2f(unsigned short b) {
  union { unsigned u; float f; } v; v.u = ((unsigned)b) << 16;
  return v.f;
}

// ---------------- prep: z->f16, w->f16 MFMA B-frags [T][kk][t][lane][8], deg count ----------------
__global__ void k_prep(const float* __restrict__ nattr, const float* __restrict__ ndeg,
                       const float* __restrict__ w0, const float* __restrict__ w1,
                       const float* __restrict__ w2, const float* __restrict__ w3,
                       const float* __restrict__ w4, const float* __restrict__ W1g,
                       const int* __restrict__ edst, int* __restrict__ cnt,
                       _Float16* __restrict__ zh, float* __restrict__ dis,
                       _Float16* __restrict__ wrp, unsigned short* __restrict__ w1p,
                       int N, int E) {
  int i = blockIdx.x * 256 + threadIdx.x;
  int nz = N * NC;
  if (i < nz) { zh[i] = (_Float16)nattr[i]; return; }
  i -= nz;
  if (i < N) { dis[i] = rsqrtf(ndeg[i]); return; }
  i -= N;
  if (i < 5 * 32768) {
    int T = i >> 15, r = i & 32767;
    int tile = r >> 9, l = (r >> 3) & 63, b = r & 7;
    int kk = tile >> 1, t = tile & 1;
    int v = 8 * (l >> 4) + b, k = t * 16 + (l & 15);
    const float* w = (T == 0) ? w0 : (T == 1) ? w1 : (T == 2) ? w2 : (T == 3) ? w3 : w4;
    wrp[T * 32768 + (tile * 64 + l) * 8 + b] = (_Float16)(w[kk * 1024 + v * 32 + k] * (1.0f / 32.0f));
    return;
  }
  i -= 5 * 32768;
  if (i < 6144) {
    int c = i / 3072, r2 = i % 3072;
    int t = r2 >> 9, l = (r2 >> 3) & 63, b = r2 & 7;
    int k = 32 * c + 8 * (l >> 4) + b, col = 16 * t + (l & 15);
    w1p[i] = f2bf(W1g[k * 96 + col] * 0.125f);
    return;
  }
  i -= 6144;
  if (i < E) atomicAdd(&cnt[edst[i]], 1);
}

// ---------------- nf+mask: pure-MFMA outer-product fctp, 16 nodes/wave, 1 wave/block ----------------
__global__ __launch_bounds__(64) void k_nfmask(
    const _Float16* __restrict__ wrp, const _Float16* __restrict__ zh,
    const float* __restrict__ x_in, const float* __restrict__ dis,
    float* __restrict__ nf, float* __restrict__ maskb, int N) {
  __shared__ float xs[32 * 17];  // [kk][row], stride 17 banks
  int lane = threadIdx.x;
  int nbase = blockIdx.x * 16;
  for (int i = lane; i < 512; i += 64) {
    int row = i >> 5, kk = i & 31;
    xs[kk * 17 + row] = x_in[(nbase + row) * 32 + kk];
  }
  f16x8 zf = *(const f16x8*)(zh + (nbase + (lane & 15)) * 32 + 8 * (lane >> 4));
  __syncthreads();

  f32x4 acc[2][2];
#pragma unroll
  for (int T = 0; T < 2; ++T)
#pragma unroll
    for (int t = 0; t < 2; ++t) { f32x4 z4 = {0.f,0.f,0.f,0.f}; acc[T][t] = z4; }

  int row16 = lane & 15;
#pragma unroll
  for (int kk = 0; kk < 32; ++kk) {
    _Float16 xh = (_Float16)xs[kk * 17 + row16];
    f16x8 af;
#pragma unroll
    for (int b = 0; b < 8; ++b) af[b] = zf[b] * xh;
#pragma unroll
    for (int T = 0; T < 2; ++T)
#pragma unroll
      for (int t = 0; t < 2; ++t) {
        f16x8 bf = *(const f16x8*)(wrp + (size_t)T * 32768 + ((kk * 2 + t) * 64 + lane) * 8);
        acc[T][t] = __builtin_amdgcn_mfma_f32_16x16x32_f16(af, bf, acc[T][t], 0, 0, 0);
      }
  }
  int rg = lane >> 4, c0 = lane & 15;
#pragma unroll
  for (int t = 0; t < 2; ++t)
#pragma unroll
    for (int r = 0; r < 4; ++r) {
      int gn = nbase + 4 * rg + r;
      int k = t * 16 + c0;
      nf[gn * 32 + k] = acc[0][t][r] * dis[gn];
      maskb[gn * 32 + k] = acc[1][t][r];
    }
}

// ---------------- CSR scans ----------------
__global__ __launch_bounds__(512) void k_scan1(const int* __restrict__ cnt, int* __restrict__ exl,
                                               int* __restrict__ bsum, int n) {
  __shared__ int s[512];
  int t = threadIdx.x;
  int i = blockIdx.x * 512 + t;
  int v = (i < n) ? cnt[i] : 0;
  s[t] = v;
  __syncthreads();
  for (int off = 1; off < 512; off <<= 1) {
    int add = (t >= off) ? s[t - off] : 0;
    __syncthreads();
    s[t] += add;
    __syncthreads();
  }
  if (i < n) exl[i] = s[t] - v;
  if (t == 511) bsum[blockIdx.x] = s[511];
}
__global__ void k_scan2(int* __restrict__ bsum, int nb) {
  __shared__ int s[128];
  int t = threadIdx.x;
  int v = (t < nb) ? bsum[t] : 0;
  s[t] = v;
  __syncthreads();
  for (int off = 1; off < 128; off <<= 1) {
    int add = (t >= off) ? s[t - off] : 0;
    __syncthreads();
    s[t] += add;
    __syncthreads();
  }
  if (t < nb) bsum[t] = s[t] - v;
}
__global__ void k_scan3(int* __restrict__ off, const int* __restrict__ bbase,
                        int* __restrict__ cur, int N, int E) {
  int i = blockIdx.x * 256 + threadIdx.x;
  if (i < N) {
    int o = off[i] + bbase[i >> 9];
    off[i] = o;
    cur[i] = o;
  } else if (i == N) {
    off[N] = E;
  }
}
__global__ void k_fill(const int* __restrict__ dst, int* __restrict__ cur,
                       int* __restrict__ pos, int E) {
  int i = blockIdx.x * 256 + threadIdx.x;
  if (i < E) pos[i] = atomicAdd(&cur[dst[i]], 1);
}

// ---------------- edge MLP -> unified 256B record scattered to CSR slot (unchanged) ----------------
#define TS 136
__global__ __launch_bounds__(256) void k_mlp(const float* __restrict__ el,
                                             const float* __restrict__ W0g,
                                             const unsigned short* __restrict__ w1p,
                                             const int* __restrict__ pos,
                                             const int* __restrict__ esrc,
                                             const float* __restrict__ eattr,
                                             unsigned short* __restrict__ recs, int E) {
  __shared__ float w0s[NB * NH];
  __shared__ __align__(16) unsigned short tile[64 * TS];
  __shared__ int posl[64];
  int tid = threadIdx.x;
  int ebase = blockIdx.x * 64;
  for (int i = tid; i < NB * NH; i += 256) w0s[i] = W0g[i] * 0.31622776601683794f;
  if (tid < 64) posl[tid] = pos[ebase + tid];

  for (int i = tid; i < 64 * 10; i += 256) {
    int le = i / 10, c = i - le * 10;
    int e = ebase + le;
    if (c < 9) tile[le * TS + 96 + c] = f2bf(eattr[(size_t)e * 9 + c]);
    else       tile[le * TS + 105] = (unsigned short)esrc[e];
  }
  __syncthreads();

  int lane = tid & 63, wv = tid >> 6;
  int eloc0 = wv * 16;
  int erow = ebase + eloc0 + (lane & 15);
  float elr[NB];
#pragma unroll
  for (int b = 0; b < NB; ++b) elr[b] = el[erow * NB + b];
  int g8 = 8 * (lane >> 4);
  bf16x8 afr[2];
#pragma unroll
  for (int c = 0; c < 2; ++c) {
#pragma unroll
    for (int b = 0; b < 8; ++b) {
      int j = 32 * c + g8 + b;
      float p = 0.f;
#pragma unroll
      for (int q = 0; q < NB; ++q) p = fmaf(elr[q], w0s[q * NH + j], p);
      float h = p / (1.f + __expf(-p));
      afr[c][b] = (short)f2bf(h);
    }
  }
  f32x4 acc[6];
#pragma unroll
  for (int t = 0; t < 6; ++t) { f32x4 z4 = {0.f, 0.f, 0.f, 0.f}; acc[t] = z4; }
#pragma unroll
  for (int c = 0; c < 2; ++c) {
#pragma unroll
    for (int t = 0; t < 6; ++t) {
      bf16x8 bfr = *(const bf16x8*)(w1p + ((c * 6 + t) * 64 + lane) * 8);
      acc[t] = __builtin_amdgcn_mfma_f32_16x16x32_bf16(afr[c], bfr, acc[t], 0, 0, 0);
    }
  }
  int rb = 4 * (lane >> 4);
#pragma unroll
  for (int t = 0; t < 6; ++t) {
    int col = 16 * t + (lane & 15);
#pragma unroll
    for (int r = 0; r < 4; ++r) tile[(eloc0 + rb + r) * TS + col] = f2bf(acc[t][r]);
  }
  __syncthreads();
  for (int ch = tid; ch < 64 * 16; ch += 256) {
    int le = ch >> 4, seg = ch & 15;
    size_t p = (size_t)posl[le];
    *(uint4*)(recs + p * REC + seg * 8) = *(const uint4*)(&tile[le * TS + seg * 8]);
  }
}

// ---------------- gather (unchanged) ----------------
__global__ __launch_bounds__(256) void k_gather(
    const int* __restrict__ off, const unsigned short* __restrict__ recs,
    const float* __restrict__ nf, const float* __restrict__ dis,
    float* __restrict__ a_all, int N) {
  int hw = blockIdx.x * 4 + (threadIdx.x >> 6);
  int lane = threadIdx.x & 63;
  int u = lane & 31, half = lane >> 5;
  if (hw >= N) return;
  int beg = off[hw], end = off[hw + 1];
  float a0 = 0, a1x = 0, a1y = 0, a1z = 0, b0 = 0, b1 = 0, b2 = 0, b3 = 0, b4 = 0;
  float xs_next = 0.f;
  int p0 = beg + half;
  if (p0 < end) {
    int s0 = recs[(size_t)p0 * REC + 105];
    xs_next = nf[(size_t)s0 * 32 + u];
  }
  for (int p = p0; p < end; p += 2) {
    float xs = xs_next;
    int p2 = p + 2;
    if (p2 < end) {
      int s2 = recs[(size_t)p2 * REC + 105];
      xs_next = nf[(size_t)s2 * 32 + u];
    }
    const unsigned short* r = recs + (size_t)p * REC;
    float w0 = bf2f(r[u]), w1 = bf2f(r[32 + u]), w2 = bf2f(r[64 + u]);
    float t0 = w0 * xs, t1 = w1 * xs, t2 = w2 * xs;
    a0  = fmaf(t0, bf2f(r[96]), a0);
    a1x = fmaf(t1, bf2f(r[97]), a1x);
    a1y = fmaf(t1, bf2f(r[98]), a1y);
    a1z = fmaf(t1, bf2f(r[99]), a1z);
    b0  = fmaf(t2, bf2f(r[100]), b0);
    b1  = fmaf(t2, bf2f(r[101]), b1);
    b2  = fmaf(t2, bf2f(r[102]), b2);
    b3  = fmaf(t2, bf2f(r[103]), b3);
    b4  = fmaf(t2, bf2f(r[104]), b4);
  }
  a0 += __shfl_xor(a0, 32, 64);  a1x += __shfl_xor(a1x, 32, 64);
  a1y += __shfl_xor(a1y, 32, 64); a1z += __shfl_xor(a1z, 32, 64);
  b0 += __shfl_xor(b0, 32, 64);  b1 += __shfl_xor(b1, 32, 64);
  b2 += __shfl_xor(b2, 32, 64);  b3 += __shfl_xor(b3, 32, 64);
  b4 += __shfl_xor(b4, 32, 64);
  if (half == 0) {
    float d = dis[hw];
    float* ar = a_all + (size_t)hw * 288;
    ar[0 * 32 + u] = a0 * d;
    ar[1 * 32 + u] = a1x * d;
    ar[2 * 32 + u] = a1y * d;
    ar[3 * 32 + u] = a1z * d;
    ar[4 * 32 + u] = b0 * d;
    ar[5 * 32 + u] = b1 * d;
    ar[6 * 32 + u] = b2 * d;
    ar[7 * 32 + u] = b3 * d;
    ar[8 * 32 + u] = b4 * d;
  }
}

// ---------------- out: pure-MFMA outer-product fctp, 9 m-columns, kk-outer ----------------
__global__ __launch_bounds__(64) void k_out(
    const _Float16* __restrict__ wrp, const _Float16* __restrict__ zh,
    const float* __restrict__ a_all, const float* __restrict__ maskb,
    float* __restrict__ out, int N) {
  __shared__ float xs[288 * 17];  // [c=m*32+kk][row], stride 17
  int lane = threadIdx.x;
  int nbase = blockIdx.x * 16;
  for (int i = lane; i < 16 * 288; i += 64) {
    int row = i / 288, c = i - row * 288;
    xs[c * 17 + row] = a_all[(size_t)(nbase + row) * 288 + c];
  }
  f16x8 zf = *(const f16x8*)(zh + (nbase + (lane & 15)) * 32 + 8 * (lane >> 4));
  __syncthreads();

  f32x4 acc[9][2];
#pragma unroll
  for (int m = 0; m < 9; ++m)
#pragma unroll
    for (int t = 0; t < 2; ++t) { f32x4 z4 = {0.f,0.f,0.f,0.f}; acc[m][t] = z4; }

  int row16 = lane & 15;
  for (int kk = 0; kk < 32; ++kk) {
    f16x8 bfr[3][2];
#pragma unroll
    for (int T = 0; T < 3; ++T)
#pragma unroll
      for (int t = 0; t < 2; ++t)
        bfr[T][t] = *(const f16x8*)(wrp + (size_t)(2 + T) * 32768 + ((kk * 2 + t) * 64 + lane) * 8);
#pragma unroll
    for (int m = 0; m < 9; ++m) {
      _Float16 xh = (_Float16)xs[(m * 32 + kk) * 17 + row16];
      f16x8 af;
#pragma unroll
      for (int b = 0; b < 8; ++b) af[b] = zf[b] * xh;
      int T = (m == 0) ? 0 : (m < 4) ? 1 : 2;
      acc[m][0] = __builtin_amdgcn_mfma_f32_16x16x32_f16(af, bfr[T][0], acc[m][0], 0, 0, 0);
      acc[m][1] = __builtin_amdgcn_mfma_f32_16x16x32_f16(af, bfr[T][1], acc[m][1], 0, 0, 0);
    }
  }

  const float c_s = 0.3826834323650898f;
  const float c_x = 0.9238795325112867f;
  int rg = lane >> 4, c0 = lane & 15;
#pragma unroll
  for (int t = 0; t < 2; ++t)
#pragma unroll
    for (int r = 0; r < 4; ++r) {
      int gn = nbase + 4 * rg + r;
      int k = t * 16 + c0;
      float* orow = out + (size_t)gn * 288;
      orow[k] = c_x * acc[0][t][r] + c_s * maskb[(size_t)gn * 32 + k];
#pragma unroll
      for (int m = 0; m < 3; ++m) orow[32 + k * 3 + m] = acc[1 + m][t][r];
#pragma unroll
      for (int m = 0; m < 5; ++m) orow[128 + k * 5 + m] = acc[4 + m][t][r];
    }
}

extern "C" void kernel_launch(void* const* d_in, const int* in_sizes, int n_in,
                              void* d_out, int out_size, void* d_ws, size_t ws_size,
                              hipStream_t stream) {
  const float* node_input = (const float*)d_in[0];
  const float* node_attr  = (const float*)d_in[1];
  const float* node_deg   = (const float*)d_in[2];
  const int*   edge_src   = (const int*)d_in[3];
  const int*   edge_dst   = (const int*)d_in[4];
  const float* edge_attr  = (const float*)d_in[5];
  const float* el_emb     = (const float*)d_in[6];
  const float* w_lin_in   = (const float*)d_in[7];
  const float* w_lin_mask = (const float*)d_in[8];
  const float* w_out0     = (const float*)d_in[9];
  const float* w_out1     = (const float*)d_in[10];
  const float* w_out2     = (const float*)d_in[11];
  const float* W0         = (const float*)d_in[12];
  const float* W1         = (const float*)d_in[13];
  int N = in_sizes[0] / 32;
  int E = in_sizes[3];
  float* out = (float*)d_out;

  char* p = (char*)d_ws;
  auto carve = [&](size_t bytes) { char* r = p; p += (bytes + 255) & ~(size_t)255; return r; };
  unsigned short* recs = (unsigned short*)carve((size_t)E * REC * 2);  // 153.6MB
  float* a_all        = (float*)carve((size_t)N * 288 * 4);
  float* nf           = (float*)carve((size_t)N * 32 * 4);
  float* maskb        = (float*)carve((size_t)N * 32 * 4);
  _Float16* zh        = (_Float16*)carve((size_t)N * 32 * 2);
  float* dis          = (float*)carve((size_t)N * 4);
  _Float16* wrp       = (_Float16*)carve(5 * 32768 * 2);
  unsigned short* w1p = (unsigned short*)carve(6144 * 2);
  int* cnt            = (int*)carve((size_t)N * 4);
  int* off            = (int*)carve((size_t)(N + 1) * 4);
  int* cur            = (int*)carve((size_t)N * 4);
  int* pos            = (int*)carve((size_t)E * 4);
  int* bsum           = (int*)carve(1024);

  hipMemsetAsync(cnt, 0, (size_t)N * 4, stream);

  int tot = N * 32 + N + 5 * 32768 + 6144 + E;
  k_prep<<<(tot + 255) / 256, 256, 0, stream>>>(node_attr, node_deg, w_lin_in, w_lin_mask,
                                                w_out0, w_out1, w_out2, W1, edge_dst, cnt,
                                                zh, dis, wrp, w1p, N, E);

  k_nfmask<<<N / 16, 64, 0, stream>>>(wrp, zh, node_input, dis, nf, maskb, N);

  int nb1 = (N + 511) / 512;
  k_scan1<<<nb1, 512, 0, stream>>>(cnt, off, bsum, N);
  k_scan2<<<1, 128, 0, stream>>>(bsum, nb1);
  k_scan3<<<(N + 1 + 255) / 256, 256, 0, stream>>>(off, bsum, cur, N, E);
  k_fill<<<(E + 255) / 256, 256, 0, stream>>>(edge_dst, cur, pos, E);

  k_mlp<<<E / 64, 256, 0, stream>>>(el_emb, W0, w1p, pos, edge_src, edge_attr, recs, E);
  k_gather<<<(N + 3) / 4, 256, 0, stream>>>(off, recs, nf, dis, a_all, N);

  k_out<<<N / 16, 64, 0, stream>>>(wrp, zh, a_all, maskb, out, N);
}